// Round 13
// baseline (903.952 us; speedup 1.0000x reference)
//
#include <hip/hip_runtime.h>

// WaveGC wavelet conv. Round 24 = R23 (209.0us) restructured into a
// persistent 2-launch pipeline. R23 audit: filter 67 + prep ~10 leaves
// ~130us for st4/st5/st6+gaps vs ~60us of traffic at the demonstrated
// 7.8 TB/s staging -- the GEMMs run at 1.5 blocks/CU (384 blocks) and pay
// 4 launch gaps. Fix: one mega-kernel, 768 blocks (= exactly 3/CU via
// launch_bounds(256,3); LDS 32KB; all co-resident by construction):
//   phase F: filter(544 tiles, XCD-chunked) + st1(384) grid-strided
//   barrier -> st4 (768 items, BN=32) -> barrier -> st5 -> barrier -> st6
// Barrier = arrive-counter + agent-scope atomic spin + __threadfence both
// sides (writes flush to shared L3; reader XCD-L2s never cached others'
// lines -- per-tile-disjoint write regions). ctr zeroed by prep_all each
// iteration (graph-replay safe). st4/st5/st6 use the PROVEN gemm_body with
// a new NBF (B-frag count) param: BN=32 -> 768 blocks = 3/CU (R20/R21
// "more blocks" lever; +50% staged bytes for 2x residency).
//
//  prep_all : A4 | xh | Wg/Wf LDS-transpose | bgp | zero sumsq+ctr
//  mega     : F=A A^T + sumsq, PT=NT(WgT,x) || st4 || st5 || st6
//
// ws: F16 @0 (33.5M) | A4 @33.5M | xh @67.1M | WgTh | PTh | HTh | combh
//     | WfTh | rowss @82.44M | bgp @82.477M | ctr @82.481M

#define NN 2048
#define NPW 4194304L   // N*N

typedef _Float16 f16x8 __attribute__((ext_vector_type(8)));
typedef float f32x4  __attribute__((ext_vector_type(4)));

__device__ inline unsigned short f16_rne(float f) {
    union { _Float16 h; unsigned short u; } c;
    c.h = (_Float16)f;
    return c.u;
}

__device__ inline void load_lds16(const void* g, void* l) {
    __builtin_amdgcn_global_load_lds(
        (const __attribute__((address_space(1))) unsigned int*)(unsigned long)g,
        (__attribute__((address_space(3))) unsigned int*)(unsigned long)l,
        16, 0, 0);
}

// Device-scope grid barrier: all 768 blocks co-resident by construction.
// Monotone counter; target = nblocks * phase_index. Release/acquire via
// agent-scope atomics + __threadfence (L2 writeback to shared L3).
__device__ __forceinline__ void grid_bar(unsigned* ctr, unsigned target) {
    __syncthreads();
    __threadfence();
    if (threadIdx.x == 0) {
        __hip_atomic_fetch_add(ctr, 1u, __ATOMIC_RELEASE,
                               __HIP_MEMORY_SCOPE_AGENT);
        while (__hip_atomic_load(ctr, __ATOMIC_ACQUIRE,
                                 __HIP_MEMORY_SCOPE_AGENT) < target)
            __builtin_amdgcn_s_sleep(8);
    }
    __syncthreads();
    __threadfence();
}

// ---------------------------------------------------------------------------
// Shared NT-GEMM body (proven R23). FI: BM = FI*64. NBF: BN = NBF*16.
// BIASM: 0 none, 1 per-row, 2 per-col. TSTORE: C transposed.
// SCALE: 1 -> acc *= 1/max(sqrt(scaleV[col]),1e-12).
// ---------------------------------------------------------------------------
template<int BIASM, bool RELU, bool OUTF32, bool TSTORE, int SCALE, int FI, int NBF>
__device__ __forceinline__ void gemm_body(
    const unsigned short* __restrict__ Ah,
    const unsigned short* __restrict__ Bh,
    unsigned short* __restrict__ Ch, float* __restrict__ Cf,
    const float* __restrict__ bias, const float* __restrict__ scaleV,
    int K, int a_rows, int b_rows, int i_valid, int j_valid, int ldc,
    int i0, int j0,
    unsigned short (&sAh)[2][FI * 64 * 64],
    unsigned short (&sBh)[2][NBF * 16 * 64])
{
    int tid = threadIdx.x;
    int lane = tid & 63, w = tid >> 6;
    int wr = w * (FI * 16);
    int q = lane >> 4, r15 = lane & 15;

    auto stage = [&](int buf, int k0) {
        #pragma unroll
        for (int p = 0; p < FI * 2; ++p) {
            int c = p * 256 + tid;
            int row = c >> 3;
            int gsw = (c & 7) ^ (row & 7);
            int ra = min(i0 + row, a_rows - 1);
            int ldst = (p * 256 + tid) * 8;
            load_lds16(Ah + (long)ra * K + k0 + gsw * 8, &sAh[buf][ldst]);
        }
        #pragma unroll
        for (int p = 0; p < NBF / 2; ++p) {
            int c = p * 256 + tid;
            int row = c >> 3;
            int gsw = (c & 7) ^ (row & 7);
            int rb = min(j0 + row, b_rows - 1);
            int ldst = (p * 256 + tid) * 8;
            load_lds16(Bh + (long)rb * K + k0 + gsw * 8, &sBh[buf][ldst]);
        }
    };

    f32x4 acc[FI][NBF];
    #pragma unroll
    for (int i = 0; i < FI; ++i)
        #pragma unroll
        for (int j = 0; j < NBF; ++j)
            acc[i][j] = (f32x4){0.f, 0.f, 0.f, 0.f};

    stage(0, 0);
    __syncthreads();

    for (int k0 = 0; k0 < K; k0 += 64) {
        int cur = (k0 >> 6) & 1;
        if (k0 + 64 < K) stage(cur ^ 1, k0 + 64);

        #pragma unroll
        for (int s = 0; s < 2; ++s) {
            int g = s * 4 + q;
            f16x8 fA[FI], fB[NBF];
            #pragma unroll
            for (int f = 0; f < FI; ++f) {
                int ra = wr + f * 16 + r15;
                fA[f] = *(const f16x8*)&sAh[cur][ra * 64 + ((g ^ (ra & 7)) * 8)];
            }
            #pragma unroll
            for (int f = 0; f < NBF; ++f) {
                int rb = f * 16 + r15;
                fB[f] = *(const f16x8*)&sBh[cur][rb * 64 + ((g ^ (rb & 7)) * 8)];
            }
            #pragma unroll
            for (int fi = 0; fi < FI; ++fi)
                #pragma unroll
                for (int fj = 0; fj < NBF; ++fj)
                    acc[fi][fj] = __builtin_amdgcn_mfma_f32_16x16x32_f16(
                        fA[fi], fB[fj], acc[fi][fj], 0, 0, 0);
        }
        __syncthreads();
    }

    #pragma unroll
    for (int fi = 0; fi < FI; ++fi)
        #pragma unroll
        for (int fj = 0; fj < NBF; ++fj) {
            int col = j0 + fj * 16 + r15;
            if (col >= j_valid) continue;
            float ivc = 1.f;
            if (SCALE == 1)
                ivc = 1.f / fmaxf(sqrtf(scaleV[col]), 1e-12f);
            #pragma unroll
            for (int r = 0; r < 4; ++r) {
                int row = i0 + wr + fi * 16 + q * 4 + r;
                if (row >= i_valid) continue;
                float v = acc[fi][fj][r];
                if (SCALE == 1) v *= ivc;
                if (BIASM == 1) v += bias[row];
                if (BIASM == 2) v += bias[col];
                if (RELU) v = fmaxf(v, 0.f);
                long off = TSTORE ? ((long)col * ldc + row)
                                  : ((long)row * ldc + col);
                if (OUTF32) Cf[off] = v;
                else        Ch[off] = f16_rne(v);
            }
        }
}

// ---------------------------------------------------------------------------
// Filter tile item (R19/R23 body): 128x128 triangular tile b of A_z A_z^T,
// fp16 out + fused row/col sumsq. Off-diag XCD-chunked; diag last.
// ---------------------------------------------------------------------------
__device__ __forceinline__ void filter_item(
    int b, int noff, const unsigned short* __restrict__ AhB,
    unsigned short* __restrict__ F16B, float* __restrict__ ssB, long sA,
    unsigned short* sAh, unsigned short* sBh)
{
    const int K = NN, N = NN;
    int tid = threadIdx.x;
    int lane = tid & 63, w = tid >> 6;
    int wbase = w * 64;
    int wr = w * 32;
    int q = lane >> 4, r15 = lane & 15;

    int z, it, jt;
    if (b < noff) {               // off-diag, XCD-chunked bijection
        int idx = (b & 7) * (noff >> 3) + (b >> 3);
        z = idx / 120;
        int r = idx - z * 120;
        int span = 15; it = 0;
        while (r >= span) { r -= span; ++it; --span; }
        jt = it + 1 + r;
    } else {                      // diagonal: 16 per t, last
        int d = b - noff;
        z = d >> 4;
        it = d & 15;
        jt = it;
    }
    int i0 = it * 128, j0 = jt * 128;
    bool diag = (jt == it);
    bool mirror = !diag;

    const unsigned short* Ah = AhB + z * sA;
    unsigned short* F = F16B + (long)z * NPW;
    float* sumsq = ssB + z * NN;

    f32x4 acc[2][8];
    #pragma unroll
    for (int i = 0; i < 2; ++i)
        #pragma unroll
        for (int j = 0; j < 8; ++j)
            acc[i][j] = (f32x4){0.f, 0.f, 0.f, 0.f};

    for (int k0 = 0; k0 < K; k0 += 64) {
        #pragma unroll
        for (int p = 0; p < 4; ++p) {
            int c = p * 256 + wbase + lane;
            int row = c >> 3;
            int gsw = (c & 7) ^ (row & 7);
            long off = (long)(i0 + row) * K + k0 + gsw * 8;
            int ldst = (p * 256 + wbase) * 8;
            load_lds16(Ah + off, &sAh[ldst]);
        }
        if (!diag) {
            #pragma unroll
            for (int p = 0; p < 4; ++p) {
                int c = p * 256 + wbase + lane;
                int row = c >> 3;
                int gsw = (c & 7) ^ (row & 7);
                long off = (long)(j0 + row) * K + k0 + gsw * 8;
                int ldst = (p * 256 + wbase) * 8;
                load_lds16(Ah + off, &sBh[ldst]);
            }
        }
        __syncthreads();

        const unsigned short* bh = diag ? sAh : sBh;

        #pragma unroll
        for (int s = 0; s < 2; ++s) {
            int g = s * 4 + q;
            f16x8 fA[2], fB[8];
            #pragma unroll
            for (int f = 0; f < 2; ++f) {
                int ra = wr + f * 16 + r15;
                fA[f] = *(const f16x8*)&sAh[ra * 64 + ((g ^ (ra & 7)) * 8)];
            }
            #pragma unroll
            for (int f = 0; f < 8; ++f) {
                int rb = f * 16 + r15;
                fB[f] = *(const f16x8*)&bh[rb * 64 + ((g ^ (rb & 7)) * 8)];
            }
            #pragma unroll
            for (int fi = 0; fi < 2; ++fi)
                #pragma unroll
                for (int fj = 0; fj < 8; ++fj)
                    acc[fi][fj] = __builtin_amdgcn_mfma_f32_16x16x32_f16(
                        fA[fi], fB[fj], acc[fi][fj], 0, 0, 0);
        }
        __syncthreads();
    }

    #pragma unroll
    for (int fi = 0; fi < 2; ++fi)
        #pragma unroll
        for (int r = 0; r < 4; ++r) {
            float s = 0.f;
            #pragma unroll
            for (int fj = 0; fj < 8; ++fj) {
                float v = acc[fi][fj][r];
                s += v * v;
            }
            s += __shfl_xor(s, 1); s += __shfl_xor(s, 2);
            s += __shfl_xor(s, 4); s += __shfl_xor(s, 8);
            if (r15 == 0)
                atomicAdd(&sumsq[i0 + wr + fi * 16 + q * 4 + r], s);
        }

    if (mirror) {
        #pragma unroll
        for (int fj = 0; fj < 8; ++fj) {
            float s = 0.f;
            #pragma unroll
            for (int fi = 0; fi < 2; ++fi)
                #pragma unroll
                for (int r = 0; r < 4; ++r) {
                    float v = acc[fi][fj][r];
                    s += v * v;
                }
            s += __shfl_xor(s, 16); s += __shfl_xor(s, 32);
            if (lane < 16)
                atomicAdd(&sumsq[j0 + fj * 16 + lane], s);
        }
    }

    #pragma unroll
    for (int fi = 0; fi < 2; ++fi)
        #pragma unroll
        for (int fj = 0; fj < 8; ++fj) {
            int col = j0 + fj * 16 + r15;
            #pragma unroll
            for (int r = 0; r < 4; ++r) {
                int row = i0 + wr + fi * 16 + q * 4 + r;
                unsigned short h = f16_rne(acc[fi][fj][r]);
                F[(long)row * N + col] = h;
                if (mirror) F[(long)col * N + row] = h;
            }
        }
}

// ---------------------------------------------------------------------------
// Mega kernel: 768 blocks, all co-resident (LDS 32KB, launch_bounds(256,3)).
// Phase F: 928 items (544 filter + 384 st1), grid-strided.
// Phases st4/st5/st6: 768 items each (BN=32).
// ---------------------------------------------------------------------------
__global__ __launch_bounds__(256, 3)
void mega(const unsigned short* __restrict__ A4,
          unsigned short* __restrict__ F16, float* __restrict__ rowss,
          const unsigned short* __restrict__ WgTh,
          const unsigned short* __restrict__ xh,
          unsigned short* __restrict__ PTh, unsigned short* __restrict__ HTh,
          unsigned short* __restrict__ combh,
          const unsigned short* __restrict__ WfTh,
          const float* __restrict__ bgp, const float* __restrict__ bf,
          float* __restrict__ out, unsigned* __restrict__ ctr)
{
    __shared__ unsigned short smemA[2][4096];   // 16KB
    __shared__ unsigned short smemB[2][4096];   // 16KB

    using bufB2 = unsigned short[2][2048];
    bufB2& sB2 = *reinterpret_cast<bufB2*>(&smemB[0][0]);

    // ---------------- phase F: filter + st1 ----------------
    for (int item = blockIdx.x; item < 928; item += 768) {
        if (item < 544) {
            filter_item(item, 480, A4, F16, rowss, NPW,
                        &smemA[0][0], &smemB[0][0]);
        } else {
            int b2 = item - 544;             // [0, 384)
            int jx = b2 & 31;
            int t3 = b2 >> 5;
            int iy = t3 % 3;
            int z  = t3 / 3;
            gemm_body<0, false, false, false, 0, 1, 4>(
                WgTh + (long)z * 147456L, xh,
                PTh + (long)z * 393216L, nullptr, nullptr, nullptr,
                768, 192, NN, 192, NN, NN, iy * 64, jx * 64, smemA, smemB);
        }
    }
    grid_bar(ctr, 768);

    // ---------------- phase st4: 768 items, BN=32 ----------------
    {
        int e = blockIdx.x;
        int jx = e & 63;
        int t3 = e >> 6;
        int iy = t3 % 3;
        int z  = t3 / 3;
        gemm_body<1, true, false, false, 1, 1, 2>(
            PTh + (long)z * 393216L, F16 + (long)z * NPW,
            HTh + (long)z * 393216L, nullptr,
            bgp + (long)z * 256, rowss + (long)z * NN,
            NN, 192, NN, 192, NN, NN, iy * 64, jx * 32, smemA, sB2);
    }
    grid_bar(ctr, 1536);

    // ---------------- phase st5: 768 items, BN=32, T-store ----------------
    {
        int e = blockIdx.x;
        int jx = e & 63;
        int t3 = e >> 6;
        int iy = t3 % 3;
        int z  = t3 / 3;
        gemm_body<0, false, false, true, 1, 1, 2>(
            HTh + (long)z * 393216L, F16 + (long)z * NPW,
            combh + (long)z * 192L, nullptr,
            nullptr, rowss + (long)z * NN,
            NN, 192, NN, 192, NN, 768, iy * 64, jx * 32, smemA, sB2);
    }
    grid_bar(ctr, 2304);

    // ---------------- phase st6: 768 items, BN=32 ----------------
    {
        int e = blockIdx.x;
        int jx = e % 24;
        int iy = e / 24;
        gemm_body<2, true, true, false, 0, 1, 2>(
            combh, WfTh, nullptr, out, bf, nullptr,
            768, NN, 768, NN, 768, 768, iy * 64, jx * 32, smemA, sB2);
    }
}

// ---------------------------------------------------------------------------
// prep_all: one launch, branched by block range.
//  [0,4096)      : A4 = fp16(V * sqrt(sig_t)) all 4 t; zero sumsq (b<32);
//                  bgp (b==32); zero ctr (b==33)
//  [4096,5632)   : xh = fp16(x)
//  [5632,5776)   : WgT via 64x64 LDS tile transpose
//  [5776,5920)   : WfT via 64x64 LDS tile transpose
// ---------------------------------------------------------------------------
__global__ __launch_bounds__(256)
void prep_all(const float* __restrict__ V, const float* __restrict__ sig,
              const float* __restrict__ x, const float* __restrict__ Wg,
              const float* __restrict__ Wf, const float* __restrict__ bg,
              unsigned short* __restrict__ A4, float* __restrict__ zs,
              float* __restrict__ bgp, unsigned short* __restrict__ xh,
              unsigned short* __restrict__ WgTh, unsigned short* __restrict__ WfTh,
              unsigned* __restrict__ ctr)
{
    __shared__ float tile[64][65];
    int b = blockIdx.x;
    int tid = threadIdx.x;
    if (b < 4096) {
        if (b < 32) zs[b * 256 + tid] = 0.f;
        if (b == 32) {
            #pragma unroll
            for (int p = 0; p < 4; ++p) {
                int i = p * 256 + tid;
                int t = i >> 8, n = i & 255;
                bgp[i] = (n < 192) ? bg[t * 192 + n] : 0.f;
            }
        }
        if (b == 33 && tid == 0) *ctr = 0u;
        long idx = ((long)b * 256 + tid) * 4;
        int k = (int)(idx & (NN - 1));
        float4 v = *(const float4*)(V + idx);
        float vv[4] = {v.x, v.y, v.z, v.w};
        float4 srow[4];
        #pragma unroll
        for (int i = 0; i < 4; ++i)
            srow[i] = *(const float4*)(sig + (k + i) * 4);
        #pragma unroll
        for (int t = 0; t < 4; ++t) {
            float sq[4] = {((const float*)&srow[0])[t], ((const float*)&srow[1])[t],
                           ((const float*)&srow[2])[t], ((const float*)&srow[3])[t]};
            ushort4 hi;
            hi.x = f16_rne(vv[0] * sqrtf(sq[0]));
            hi.y = f16_rne(vv[1] * sqrtf(sq[1]));
            hi.z = f16_rne(vv[2] * sqrtf(sq[2]));
            hi.w = f16_rne(vv[3] * sqrtf(sq[3]));
            *(ushort4*)(A4 + (long)t * NPW + idx) = hi;
        }
        return;
    }
    b -= 4096;
    if (b < 1536) {   // xh
        long idx = ((long)b * 256 + tid) * 4;
        float4 v = *(const float4*)(x + idx);
        ushort4 hi;
        hi.x = f16_rne(v.x);
        hi.y = f16_rne(v.y);
        hi.z = f16_rne(v.z);
        hi.w = f16_rne(v.w);
        *(ushort4*)(xh + idx) = hi;
        return;
    }
    b -= 1536;
    if (b < 144) {    // WgT: per t, 12 k-tiles x 3 n-tiles of 64x64
        int t = b / 36, r = b - t * 36;
        int kt = r / 3, nt = r - kt * 3;
        const float* src = Wg + (long)t * 147456;
        #pragma unroll
        for (int p = 0; p < 16; ++p) {
            int i = p * 256 + tid;
            int kk = i >> 6, nn = i & 63;
            tile[kk][nn] = src[(long)(kt * 64 + kk) * 192 + nt * 64 + nn];
        }
        __syncthreads();
        #pragma unroll
        for (int p = 0; p < 16; ++p) {
            int i = p * 256 + tid;
            int nn = i >> 6, kk = i & 63;
            WgTh[(long)t * 147456 + (long)(nt * 64 + nn) * 768 + kt * 64 + kk] =
                f16_rne(tile[kk][nn]);
        }
        return;
    }
    b -= 144;
    {                 // WfT: 12 k-tiles x 12 n-tiles of 64x64
        int kt = b / 12, nt = b - kt * 12;
        #pragma unroll
        for (int p = 0; p < 16; ++p) {
            int i = p * 256 + tid;
            int kk = i >> 6, nn = i & 63;
            tile[kk][nn] = Wf[(long)(kt * 64 + kk) * 768 + nt * 64 + nn];
        }
        __syncthreads();
        #pragma unroll
        for (int p = 0; p < 16; ++p) {
            int i = p * 256 + tid;
            int nn = i >> 6, kk = i & 63;
            WfTh[(long)(nt * 64 + nn) * 768 + kt * 64 + kk] =
                f16_rne(tile[kk][nn]);
        }
    }
}

// ---------------------------------------------------------------------------
extern "C" void kernel_launch(void* const* d_in, const int* in_sizes, int n_in,
                              void* d_out, int out_size, void* d_ws, size_t ws_size,
                              hipStream_t stream)
{
    const float* x   = (const float*)d_in[0];
    const float* evc = (const float*)d_in[1];
    const float* sig = (const float*)d_in[2];
    const float* Wg  = (const float*)d_in[3];
    const float* bg  = (const float*)d_in[4];
    const float* Wf  = (const float*)d_in[5];
    const float* bf  = (const float*)d_in[6];
    float* out = (float*)d_out;

    char* w = (char*)d_ws;
    unsigned short* F16  = (unsigned short*)w;                  // 33.5M
    unsigned short* A4   = (unsigned short*)(w + 33554432L);    // 33.5M
    unsigned short* xh   = (unsigned short*)(w + 67108864L);    // 3.1M
    unsigned short* WgTh = (unsigned short*)(w + 70254592L);    // 1.2M
    unsigned short* PTh  = (unsigned short*)(w + 71827456L);    // 3.1M
    unsigned short* HTh  = (unsigned short*)(w + 74973184L);    // 3.1M
    unsigned short* combh= (unsigned short*)(w + 78118912L);    // 3.1M
    unsigned short* WfTh = (unsigned short*)(w + 81264640L);    // 1.2M
    float* rowss = (float*)(w + 82444288L);                     // 32K
    float* bgp   = (float*)(w + 82477056L);                     // 4K
    unsigned* ctr= (unsigned*)(w + 82481152L);                  // 4B

    prep_all<<<5920, 256, 0, stream>>>(
        evc, sig, x, Wg, Wf, bg, A4, rowss, bgp, xh, WgTh, WfTh, ctr);

    mega<<<768, 256, 0, stream>>>(
        A4, F16, rowss, WgTh, xh, PTh, HTh, combh, WfTh, bgp, bf, out, ctr);
}